// Round 18
// baseline (776.679 us; speedup 1.0000x reference)
//
#include <hip/hip_runtime.h>
#include <math.h>

#define MTOK 16384
#define NEXP 256
#define KDIM 7168

#define CAPR 1024
#define KSPLIT 8
#define KCH (KDIM / KSPLIT)   // 896
#define TAU 8e-6f

#define NKC 224               // K-chunks of 32 (full K)
#define NSTEP_H 56            // BK=64 steps per K-half (K/2 = 3584)
// Wfrag layout: [hilo][nt 0..15][kc 0..223][lane 0..63][8 f16]

typedef _Float16 f16;
typedef __attribute__((ext_vector_type(8))) f16 f16x8;
typedef __attribute__((ext_vector_type(4))) f16 f16x4;
typedef __attribute__((ext_vector_type(4))) float f32x4;

__device__ __forceinline__ void cvt_hilo4(const float4 a, f16x4* h, f16x4* l) {
    float xs[4] = {a.x, a.y, a.z, a.w};
#pragma unroll
    for (int e = 0; e < 4; ++e) {
        f16 hh = (f16)xs[e];
        (*h)[e] = hh;
        (*l)[e] = (f16)((xs[e] - (float)hh) * 2048.f);
    }
}

// ============ K0: W -> Wfrag (MFMA B-fragment order, hi/lo split) ============
__global__ void wconv_k(const float* __restrict__ W, f16* __restrict__ Wfrag,
                        int* __restrict__ count) {
    if (blockIdx.x == 0 && threadIdx.x == 0) *count = 0;   // fused init
    const int e  = blockIdx.x;
    const int kc = threadIdx.x;
    if (kc >= NKC) return;
    const int nt  = e >> 4;
    const int col = e & 15;
    const float* src = W + (size_t)e * KDIM + kc * 32;
    float x[32];
#pragma unroll
    for (int i = 0; i < 8; ++i) {
        float4 v = *(const float4*)(src + i * 4);
        x[i * 4 + 0] = v.x; x[i * 4 + 1] = v.y; x[i * 4 + 2] = v.z; x[i * 4 + 3] = v.w;
    }
#pragma unroll
    for (int k8 = 0; k8 < 4; ++k8) {
        f16x8 h, l;
#pragma unroll
        for (int j = 0; j < 8; ++j) {
            float xv = x[k8 * 8 + j];
            f16 hh = (f16)xv;
            h[j] = hh;
            l[j] = (f16)((xv - (float)hh) * 2048.f);
        }
        const size_t lanepos = (size_t)(k8 * 16 + col) * 8;
        *(f16x8*)(Wfrag + (((size_t)(0 * 16 + nt) * NKC + kc) << 9) + lanepos) = h;
        *(f16x8*)(Wfrag + (((size_t)(1 * 16 + nt) * NKC + kc) << 9) + lanepos) = l;
    }
}

// ============ K1: fp16x2-split MFMA GEMM, K-SPLIT x2 (v16) ============
// v10 internals byte-identical, but each block computes HALF of K (56 steps)
// and writes f32 partials P[kh]. Grid 512 = 2 independent 8-wave blocks per
// CU (4 waves/SIMD, separate barrier domains -> phases desync, pipes overlap).
__launch_bounds__(512, 4)
__global__ void gemm_v16_k(const float* __restrict__ X,
                           const f16* __restrict__ Wfrag,
                           float* __restrict__ P) {
    __shared__ f16 A_lds[2][2][8][128][8];   // 64 KB

    const int tid  = threadIdx.x;
    const int lane = tid & 63;
    const int w    = tid >> 6;
    const int wr   = w >> 2;
    const int wc   = w & 3;

    const int bid  = blockIdx.x;        // 0..511
    const int kh   = bid >> 8;          // 0..1 (K half)
    const int id   = bid & 255;         // v10 mapping on the rest
    const int xcd  = id & 7;
    const int nb   = xcd >> 2;
    const int mb   = (id >> 3) * 4 + (xcd & 3);
    const int m0 = mb * 128;
    const int n0 = nb * 128;

    // A staging (coalesced, v10): thread t -> row t>>2, k-lane t&3; + K-half off
    const int arow = tid >> 2;
    const int kl   = tid & 3;
    const float* xg = X + (size_t)(m0 + arow) * KDIM + kh * (KDIM / 2) + kl * 4;
    const int ghalf = (kl & 1) * 4;
    const int gbase = kl >> 1;

    const int fr = lane & 15;
    const int fq = lane >> 4;

    // B fragment bases (+ K-half chunk offset folded in)
    const size_t khoff = ((size_t)(kh * 112)) << 9;
    const int ntb = nb * 8 + wc * 2;
    const f16* wpH0 = Wfrag + (((size_t)(ntb + 0)  * NKC) << 9) + khoff + lane * 8;
    const f16* wpH1 = Wfrag + (((size_t)(ntb + 1)  * NKC) << 9) + khoff + lane * 8;
    const f16* wpL0 = Wfrag + (((size_t)(ntb + 16) * NKC) << 9) + khoff + lane * 8;
    const f16* wpL1 = Wfrag + (((size_t)(ntb + 17) * NKC) << 9) + khoff + lane * 8;

    f32x4 accA[4][2];
    f32x4 accB[4][2];
#pragma unroll
    for (int i = 0; i < 4; ++i)
#pragma unroll
        for (int j = 0; j < 2; ++j) { accA[i][j] = (f32x4)0.f; accB[i][j] = (f32x4)0.f; }

    float4 aE0, aE1, aE2, aE3, aO0, aO1, aO2, aO3;
    f16x8 p0, p1, p2, p3, p4, p5, p6, p7;
    f16x8 q0, q1, q2, q3, q4, q5, q6, q7;

#define A_LOAD4(R0_, R1_, R2_, R3_, STEP_) do {                             \
        const int st_ = (STEP_) < NSTEP_H ? (STEP_) : (NSTEP_H - 1);        \
        const float* p_ = xg + (size_t)st_ * 64;                            \
        R0_ = *(const float4*)(p_ + 0);                                     \
        R1_ = *(const float4*)(p_ + 16);                                    \
        R2_ = *(const float4*)(p_ + 32);                                    \
        R3_ = *(const float4*)(p_ + 48);                                    \
    } while (0)

#define B_LOAD8(R0_,R1_,R2_,R3_,R4_,R5_,R6_,R7_, STEP_) do {                \
        const int st_ = (STEP_) < NSTEP_H ? (STEP_) : (NSTEP_H - 1);        \
        const size_t oa_ = ((size_t)(st_ * 2))     << 9;                    \
        const size_t ob_ = ((size_t)(st_ * 2 + 1)) << 9;                    \
        R0_ = *(const f16x8*)(wpH0 + oa_);                                  \
        R1_ = *(const f16x8*)(wpH1 + oa_);                                  \
        R2_ = *(const f16x8*)(wpL0 + oa_);                                  \
        R3_ = *(const f16x8*)(wpL1 + oa_);                                  \
        R4_ = *(const f16x8*)(wpH0 + ob_);                                  \
        R5_ = *(const f16x8*)(wpH1 + ob_);                                  \
        R6_ = *(const f16x8*)(wpL0 + ob_);                                  \
        R7_ = *(const f16x8*)(wpL1 + ob_);                                  \
    } while (0)

#define ST_HG(BUF_, R_, I_) do {                                            \
        f16x4 h_, l_;                                                       \
        cvt_hilo4(R_, &h_, &l_);                                            \
        *(f16x4*)&A_lds[BUF_][0][gbase + 2 * (I_)][arow][ghalf] = h_;       \
        *(f16x4*)&A_lds[BUF_][1][gbase + 2 * (I_)][arow][ghalf] = l_;       \
    } while (0)

#define STORE_A4(BUF_, R0_, R1_, R2_, R3_) do {                             \
        ST_HG(BUF_, R0_, 0);                                                \
        ST_HG(BUF_, R1_, 1);                                                \
        ST_HG(BUF_, R2_, 2);                                                \
        ST_HG(BUF_, R3_, 3);                                                \
    } while (0)

#define MFMA16(A_, B_, C_) __builtin_amdgcn_mfma_f32_16x16x32_f16(A_, B_, C_, 0, 0, 0)

#define COMPUTE_CH(BUF_, K8O_, H0_, H1_, L0_, L1_) do {                     \
        f16x8 ah_[4], al_[4];                                               \
        _Pragma("unroll")                                                   \
        for (int mi_ = 0; mi_ < 4; ++mi_) {                                 \
            const int r_ = wr * 64 + mi_ * 16 + fr;                         \
            ah_[mi_] = *(const f16x8*)&A_lds[BUF_][0][(K8O_) + fq][r_][0];  \
            al_[mi_] = *(const f16x8*)&A_lds[BUF_][1][(K8O_) + fq][r_][0];  \
        }                                                                   \
        _Pragma("unroll")                                                   \
        for (int mi_ = 0; mi_ < 4; ++mi_) {                                 \
            accA[mi_][0] = MFMA16(ah_[mi_], H0_, accA[mi_][0]);             \
            accA[mi_][1] = MFMA16(ah_[mi_], H1_, accA[mi_][1]);             \
            accB[mi_][0] = MFMA16(ah_[mi_], L0_, accB[mi_][0]);             \
            accB[mi_][0] = MFMA16(al_[mi_], H0_, accB[mi_][0]);             \
            accB[mi_][1] = MFMA16(ah_[mi_], L1_, accB[mi_][1]);             \
            accB[mi_][1] = MFMA16(al_[mi_], H1_, accB[mi_][1]);             \
        }                                                                   \
    } while (0)

    // prologue
    A_LOAD4(aE0, aE1, aE2, aE3, 0);
    A_LOAD4(aO0, aO1, aO2, aO3, 1);
    B_LOAD8(p0, p1, p2, p3, p4, p5, p6, p7, 0);
    STORE_A4(0, aE0, aE1, aE2, aE3);
    __syncthreads();

    for (int s = 0; s < NSTEP_H; s += 2) {
        A_LOAD4(aE0, aE1, aE2, aE3, s + 2);
        B_LOAD8(q0, q1, q2, q3, q4, q5, q6, q7, s + 1);
        COMPUTE_CH(0, 0, p0, p1, p2, p3);
        COMPUTE_CH(0, 4, p4, p5, p6, p7);
        STORE_A4(1, aO0, aO1, aO2, aO3);
        __syncthreads();

        A_LOAD4(aO0, aO1, aO2, aO3, s + 3);
        B_LOAD8(p0, p1, p2, p3, p4, p5, p6, p7, s + 2);
        COMPUTE_CH(1, 0, q0, q1, q2, q3);
        COMPUTE_CH(1, 4, q4, q5, q6, q7);
        STORE_A4(0, aE0, aE1, aE2, aE3);
        __syncthreads();
    }

    // epilogue: write f32 partial (no sigmoid); P[kh][m][e]
    float* Pk = P + (size_t)kh * MTOK * NEXP;
#pragma unroll
    for (int mi = 0; mi < 4; ++mi)
#pragma unroll
        for (int ni = 0; ni < 2; ++ni) {
            const int e = n0 + wc * 32 + ni * 16 + fr;
#pragma unroll
            for (int r = 0; r < 4; ++r) {
                const int m = m0 + wr * 64 + mi * 16 + fq * 4 + r;
                Pk[(size_t)m * NEXP + e] = accA[mi][ni][r] + accB[mi][ni][r] * (1.f / 2048.f);
            }
        }
#undef A_LOAD4
#undef B_LOAD8
#undef ST_HG
#undef STORE_A4
#undef MFMA16
#undef COMPUTE_CH
}

// ============ K1b: reduce partials + sigmoid (in-place into P0 = Lf) ============
__launch_bounds__(256)
__global__ void reduce_sig_k(float* __restrict__ P) {
    const size_t i = ((size_t)blockIdx.x * 256 + threadIdx.x) * 4;
    float4 a = *(float4*)(P + i);
    float4 b = *(const float4*)(P + (size_t)MTOK * NEXP + i);
    float4 o;
    o.x = 1.f / (1.f + expf(-(a.x + b.x)));
    o.y = 1.f / (1.f + expf(-(a.y + b.y)));
    o.z = 1.f / (1.f + expf(-(a.z + b.z)));
    o.w = 1.f / (1.f + expf(-(a.w + b.w)));
    *(float4*)(P + i) = o;
}

// ================= K2: f32 routing + margin flagging =================
__launch_bounds__(256)
__global__ void route_flag_k(const float* __restrict__ S,
                             const float* __restrict__ bias,
                             float* __restrict__ out,
                             int* __restrict__ list,
                             int* __restrict__ count) {
    __shared__ float sraw[4][256];
    const int wv   = threadIdx.x >> 6;
    const int lane = threadIdx.x & 63;
    const int token = blockIdx.x * 4 + wv;
    const float NINF = -__builtin_inff();
    const float PINF =  __builtin_inff();

    const float* row = S + (size_t)token * NEXP;
    float4 v = *(const float4*)(row + lane * 4);
    *(float4*)&sraw[wv][lane * 4] = v;

    const int e0 = lane * 4;
    float4 bi4 = *(const float4*)(bias + e0);
    float b0 = v.x + bi4.x;
    float b1 = v.y + bi4.y;
    float b2 = v.z + bi4.z;
    float b3 = v.w + bi4.w;

    bool flag = false;

    float m1 = b0, m2 = NINF;
    if (b1 > m1) { m2 = m1; m1 = b1; } else if (b1 > m2) m2 = b1;
    if (b2 > m1) { m2 = m1; m1 = b2; } else if (b2 > m2) m2 = b2;
    if (b3 > m1) { m2 = m1; m1 = b3; } else if (b3 > m2) m2 = b3;
#pragma unroll
    for (int w = 1; w <= 4; w <<= 1) {
        float o1 = __shfl_xor(m1, w);
        float o2 = __shfl_xor(m2, w);
        float nm1 = fmaxf(m1, o1);
        float nm2 = fmaxf(fminf(m1, o1), fmaxf(m2, o2));
        m1 = nm1; m2 = nm2;
    }
    const float gs = m1 + m2;
    const int g = lane >> 3;

    int rank = 0;
#pragma unroll
    for (int j = 0; j < 8; ++j) {
        float gj = __shfl(gs, j * 8);
        rank += (gj > gs) || (gj == gs && j < g);
    }
    const bool sel = rank < 4;

    {
        float a = sel ? gs : PINF;
        float b = sel ? NINF : gs;
#pragma unroll
        for (int w = 1; w < 64; w <<= 1) {
            a = fminf(a, __shfl_xor(a, w));
            b = fmaxf(b, __shfl_xor(b, w));
        }
        flag |= (a - b) < 2.f * TAU;
    }

    if (!sel) { b0 = NINF; b1 = NINF; b2 = NINF; b3 = NINF; }

    int myidx = 0;
    float prev = 0.f;
#pragma unroll
    for (int it = 0; it < 9; ++it) {
        float bv = b0; int bi = e0;
        if (b1 > bv) { bv = b1; bi = e0 + 1; }
        if (b2 > bv) { bv = b2; bi = e0 + 2; }
        if (b3 > bv) { bv = b3; bi = e0 + 3; }
#pragma unroll
        for (int w = 1; w < 64; w <<= 1) {
            float ov = __shfl_xor(bv, w);
            int   oi = __shfl_xor(bi, w);
            if (ov > bv || (ov == bv && oi < bi)) { bv = ov; bi = oi; }
        }
        if (it > 0) flag |= (prev - bv) < TAU;
        prev = bv;
        if (it < 8) {
            if (lane == it) myidx = bi;
            if ((bi >> 2) == lane) {
                switch (bi & 3) {
                    case 0: b0 = NINF; break;
                    case 1: b1 = NINF; break;
                    case 2: b2 = NINF; break;
                    case 3: b3 = NINF; break;
                }
            }
        }
    }

    const bool anyflag = __any((int)flag);

    __syncthreads();

    float wval = (lane < 8) ? sraw[wv][myidx] : 0.f;
    float s = wval;
    s += __shfl_xor(s, 1);
    s += __shfl_xor(s, 2);
    s += __shfl_xor(s, 4);
    if (lane < 8) {
        float wout = wval / (s + 1e-20f) * 2.5f;
        out[(size_t)token * 8 + lane] = wout;
        out[(size_t)MTOK * 8 + (size_t)token * 8 + lane] = (float)myidx;
    }

    if (anyflag && lane == 0) {
        int f = atomicAdd(count, 1);
        if (f < CAPR) list[f] = token;
    }
}

// ================= K3: K-split f64 partial GEMM over flagged rows =================
__launch_bounds__(256)
__global__ void rescore_k(const float* __restrict__ X,
                          const float* __restrict__ W,
                          const int* __restrict__ list,
                          const int* __restrict__ count,
                          double* __restrict__ Ldp) {
    const int cnt = min(*count, CAPR);
    const int m0 = blockIdx.x * 64;
    if (m0 >= cnt) return;
    const int n0 = blockIdx.y * 64;
    const int ks = blockIdx.z;
    const int kbase = ks * KCH;

    __shared__ float As[16][66];
    __shared__ float Bs[16][66];
    const int tid = threadIdx.x;
    const int row = tid >> 2;
    const int c   = tid & 3;
    const int tm  = tid >> 4;
    const int tn  = tid & 15;

    const int gi = list[min(m0 + row, cnt - 1)];
    const float* xg = X + (size_t)gi * KDIM + c * 4;
    const float* wg = W + (size_t)(n0 + row) * KDIM + c * 4;

    double acc[4][4];
#pragma unroll
    for (int i = 0; i < 4; ++i)
#pragma unroll
        for (int j = 0; j < 4; ++j) acc[i][j] = 0.0;

    for (int k0 = kbase; k0 < kbase + KCH; k0 += 16) {
        float4 a = *(const float4*)(xg + k0);
        float4 b = *(const float4*)(wg + k0);
        __syncthreads();
        As[c * 4 + 0][row] = a.x; As[c * 4 + 1][row] = a.y;
        As[c * 4 + 2][row] = a.z; As[c * 4 + 3][row] = a.w;
        Bs[c * 4 + 0][row] = b.x; Bs[c * 4 + 1][row] = b.y;
        Bs[c * 4 + 2][row] = b.z; Bs[c * 4 + 3][row] = b.w;
        __syncthreads();
#pragma unroll
        for (int k = 0; k < 16; ++k) {
            double ad[4], bd[4];
#pragma unroll
            for (int i = 0; i < 4; ++i) ad[i] = (double)As[k][tm * 4 + i];
#pragma unroll
            for (int j = 0; j < 4; ++j) bd[j] = (double)Bs[k][tn * 4 + j];
#pragma unroll
            for (int i = 0; i < 4; ++i)
#pragma unroll
                for (int j = 0; j < 4; ++j)
                    acc[i][j] = fma(ad[i], bd[j], acc[i][j]);
        }
    }

#pragma unroll
    for (int i = 0; i < 4; ++i) {
        const int r = m0 + tm * 4 + i;
        if (r < cnt) {
#pragma unroll
            for (int j = 0; j < 4; ++j)
                Ldp[((size_t)ks * CAPR + r) * NEXP + n0 + tn * 4 + j] = acc[i][j];
        }
    }
}

// ================= K4: exact f64 routing for flagged tokens =================
__launch_bounds__(64)
__global__ void route_exact_k(const double* __restrict__ Ldp,
                              const float* __restrict__ bias,
                              const int* __restrict__ list,
                              const int* __restrict__ count,
                              float* __restrict__ out) {
    const int cnt = min(*count, CAPR);
    const int f = blockIdx.x;
    if (f >= cnt) return;
    const int lane = threadIdx.x;
    const int token = list[f];
    const double NINF = -__builtin_inf();

    const int e0 = lane * 4;
    double l0 = 0.0, l1 = 0.0, l2 = 0.0, l3 = 0.0;
#pragma unroll
    for (int s = 0; s < KSPLIT; ++s) {
        double4 p = *(const double4*)(Ldp + ((size_t)s * CAPR + f) * NEXP + e0);
        l0 += p.x; l1 += p.y; l2 += p.z; l3 += p.w;
    }

    double s0 = 1.0 / (1.0 + exp(-l0));
    double s1 = 1.0 / (1.0 + exp(-l1));
    double s2 = 1.0 / (1.0 + exp(-l2));
    double s3 = 1.0 / (1.0 + exp(-l3));

    float4 bi4 = *(const float4*)(bias + e0);
    double b0 = s0 + (double)bi4.x;
    double b1 = s1 + (double)bi4.y;
    double b2 = s2 + (double)bi4.z;
    double b3 = s3 + (double)bi4.w;

    double m1 = b0, m2 = NINF;
    if (b1 > m1) { m2 = m1; m1 = b1; } else if (b1 > m2) m2 = b1;
    if (b2 > m1) { m2 = m1; m1 = b2; } else if (b2 > m2) m2 = b2;
    if (b3 > m1) { m2 = m1; m1 = b3; } else if (b3 > m2) m2 = b3;
#pragma unroll
    for (int w = 1; w <= 4; w <<= 1) {
        double o1 = __shfl_xor(m1, w);
        double o2 = __shfl_xor(m2, w);
        double nm1 = fmax(m1, o1);
        double nm2 = fmax(fmin(m1, o1), fmax(m2, o2));
        m1 = nm1; m2 = nm2;
    }
    const double gs = m1 + m2;
    const int g = lane >> 3;

    int rank = 0;
#pragma unroll
    for (int j = 0; j < 8; ++j) {
        double gj = __shfl(gs, j * 8);
        rank += (gj > gs) || (gj == gs && j < g);
    }
    if (rank >= 4) { b0 = NINF; b1 = NINF; b2 = NINF; b3 = NINF; }

    int myidx = 0;
#pragma unroll
    for (int it = 0; it < 8; ++it) {
        double bv = b0; int bi = e0;
        if (b1 > bv) { bv = b1; bi = e0 + 1; }
        if (b2 > bv) { bv = b2; bi = e0 + 2; }
        if (b3 > bv) { bv = b3; bi = e0 + 3; }
#pragma unroll
        for (int w = 1; w < 64; w <<= 1) {
            double ov = __shfl_xor(bv, w);
            int    oi = __shfl_xor(bi, w);
            if (ov > bv || (ov == bv && oi < bi)) { bv = ov; bi = oi; }
        }
        if (lane == it) myidx = bi;
        if ((bi >> 2) == lane) {
            switch (bi & 3) {
                case 0: b0 = NINF; break;
                case 1: b1 = NINF; break;
                case 2: b2 = NINF; break;
                case 3: b3 = NINF; break;
            }
        }
    }

    double g0 = __shfl(s0, myidx >> 2);
    double g1 = __shfl(s1, myidx >> 2);
    double g2 = __shfl(s2, myidx >> 2);
    double g3 = __shfl(s3, myidx >> 2);
    const int ss = myidx & 3;
    double wval = (lane < 8) ? (ss == 0 ? g0 : ss == 1 ? g1 : ss == 2 ? g2 : g3) : 0.0;
    double s = wval;
    s += __shfl_xor(s, 1);
    s += __shfl_xor(s, 2);
    s += __shfl_xor(s, 4);
    if (lane < 8) {
        float wout = (float)(wval / (s + 1e-20) * 2.5);
        out[(size_t)token * 8 + lane] = wout;
        out[(size_t)MTOK * 8 + (size_t)token * 8 + lane] = (float)myidx;
    }
}

extern "C" void kernel_launch(void* const* d_in, const int* in_sizes, int n_in,
                              void* d_out, int out_size, void* d_ws, size_t ws_size,
                              hipStream_t stream) {
    const float* X    = (const float*)d_in[0];
    const float* W    = (const float*)d_in[1];
    const float* bias = (const float*)d_in[2];
    float* out = (float*)d_out;

    // ws layout (ws is GB-scale; poison covers it):
    //   [0, 16.8M)      P0  (becomes Lf after reduce_sig)
    //   [16.8M, 33.6M)  P1  (aliased by Ldp after reduce: P1 dead then)
    //   [33.6M, +4K)    list, cnt
    //   [33.6M+64K, ..) Wfrag
    float*  P     = (float*)d_ws;                         // P0 | P1
    float*  Lf    = (float*)d_ws;                         // == P0
    double* Ldp   = (double*)((char*)d_ws + 16777216);    // aliases P1
    int*    list  = (int*)((char*)d_ws + 2 * 16777216);
    int*    cnt   = (int*)((char*)d_ws + 2 * 16777216 + CAPR * 4);
    f16*    Wfrag = (f16*)((char*)d_ws + 2 * 16777216 + 65536);

    wconv_k<<<NEXP, 256, 0, stream>>>(W, Wfrag, cnt);

    gemm_v16_k<<<512, 512, 0, stream>>>(X, Wfrag, P);

    reduce_sig_k<<<(MTOK * NEXP) / (256 * 4), 256, 0, stream>>>(P);

    route_flag_k<<<MTOK / 4, 256, 0, stream>>>(Lf, bias, out, list, cnt);

    dim3 g3(CAPR / 64, NEXP / 64, KSPLIT);
    rescore_k<<<g3, 256, 0, stream>>>(X, W, list, cnt, Ldp);

    route_exact_k<<<CAPR, 64, 0, stream>>>(Ldp, bias, list, cnt, out);
}

// Round 19
// 372.985 us; speedup vs baseline: 2.0823x; 2.0823x over previous
//
#include <hip/hip_runtime.h>
#include <math.h>

#define MTOK 16384
#define NEXP 256
#define KDIM 7168

#define CAPR 1024
#define KSPLIT 8
#define KCH (KDIM / KSPLIT)   // 896
#define TAU 8e-6f             // ~18 sigma of pass-1 sigmoid-space noise

#define NKC 224               // K-chunks of 32
#define NSTEP 112             // BK=64 steps
// Wfrag layout: [hilo][nt 0..15][kc 0..223][lane 0..63][8 f16]

typedef _Float16 f16;
typedef __attribute__((ext_vector_type(8))) f16 f16x8;
typedef __attribute__((ext_vector_type(4))) f16 f16x4;
typedef __attribute__((ext_vector_type(4))) float f32x4;

__device__ __forceinline__ void cvt_hilo4(const float4 a, f16x4* h, f16x4* l) {
    float xs[4] = {a.x, a.y, a.z, a.w};
#pragma unroll
    for (int e = 0; e < 4; ++e) {
        f16 hh = (f16)xs[e];
        (*h)[e] = hh;
        (*l)[e] = (f16)((xs[e] - (float)hh) * 2048.f);
    }
}

// ============ K0: W -> Wfrag (MFMA B-fragment order, hi/lo split) ============
__global__ void wconv_k(const float* __restrict__ W, f16* __restrict__ Wfrag,
                        int* __restrict__ count) {
    if (blockIdx.x == 0 && threadIdx.x == 0) *count = 0;   // fused init
    const int e  = blockIdx.x;        // expert 0..255
    const int kc = threadIdx.x;       // 0..223 (256 threads, guard)
    if (kc >= NKC) return;
    const int nt  = e >> 4;
    const int col = e & 15;
    const float* src = W + (size_t)e * KDIM + kc * 32;
    float x[32];
#pragma unroll
    for (int i = 0; i < 8; ++i) {
        float4 v = *(const float4*)(src + i * 4);
        x[i * 4 + 0] = v.x; x[i * 4 + 1] = v.y; x[i * 4 + 2] = v.z; x[i * 4 + 3] = v.w;
    }
#pragma unroll
    for (int k8 = 0; k8 < 4; ++k8) {
        f16x8 h, l;
#pragma unroll
        for (int j = 0; j < 8; ++j) {
            float xv = x[k8 * 8 + j];
            f16 hh = (f16)xv;
            h[j] = hh;
            l[j] = (f16)((xv - (float)hh) * 2048.f);
        }
        const size_t lanepos = (size_t)(k8 * 16 + col) * 8;
        *(f16x8*)(Wfrag + (((size_t)(0 * 16 + nt) * NKC + kc) << 9) + lanepos) = h;
        *(f16x8*)(Wfrag + (((size_t)(1 * 16 + nt) * NKC + kc) << 9) + lanepos) = l;
    }
}

// ============ K1: fp16x2-split MFMA GEMM + sigmoid (v10 — measured best) ============
// BM=128, BN=128; 256 blocks (1/CU); 8 waves (2M x 4N), wave tile 64x32;
// BK=64 per barrier. A via LDS dbuf (64 KB) with coalesced global loads,
// distance-2 register prefetch; B direct from Wfrag with one-step register
// double-buffer. All register indexing static.
__launch_bounds__(512, 2)
__global__ void gemm_v10_k(const float* __restrict__ X,
                           const f16* __restrict__ Wfrag,
                           float* __restrict__ S) {
    __shared__ f16 A_lds[2][2][8][128][8];   // [buf][hilo][k8][row][8] = 64 KB

    const int tid  = threadIdx.x;
    const int lane = tid & 63;
    const int w    = tid >> 6;          // 0..7
    const int wr   = w >> 2;            // 0..1 (M half, 64 rows)
    const int wc   = w & 3;             // 0..3 (N quarter, 32 cols)

    // XCD-partitioned mapping: XCD 0-3 -> n-half 0, XCD 4-7 -> n-half 1
    const int id   = blockIdx.x;        // 0..255
    const int xcd  = id & 7;
    const int nb   = xcd >> 2;
    const int mb   = (id >> 3) * 4 + (xcd & 3);   // 0..127
    const int m0 = mb * 128;
    const int n0 = nb * 128;

    // A staging (coalesced): thread t -> row t>>2, k-lane t&3.
    const int arow = tid >> 2;          // 0..127
    const int kl   = tid & 3;           // 0..3
    const float* xg = X + (size_t)(m0 + arow) * KDIM + kl * 4;
    const int ghalf = (kl & 1) * 4;     // f16 offset within granule
    const int gbase = kl >> 1;          // granule base: g = gbase + 2*i

    const int fr = lane & 15;
    const int fq = lane >> 4;

    // B fragment bases: nt = nb*8 + wc*2 + {0,1}; lo at nt+16
    const int ntb = nb * 8 + wc * 2;
    const f16* wpH0 = Wfrag + (((size_t)(ntb + 0)  * NKC) << 9) + lane * 8;
    const f16* wpH1 = Wfrag + (((size_t)(ntb + 1)  * NKC) << 9) + lane * 8;
    const f16* wpL0 = Wfrag + (((size_t)(ntb + 16) * NKC) << 9) + lane * 8;
    const f16* wpL1 = Wfrag + (((size_t)(ntb + 17) * NKC) << 9) + lane * 8;

    f32x4 accA[4][2];
    f32x4 accB[4][2];
#pragma unroll
    for (int i = 0; i < 4; ++i)
#pragma unroll
        for (int j = 0; j < 2; ++j) { accA[i][j] = (f32x4)0.f; accB[i][j] = (f32x4)0.f; }

    // named prefetch registers (all statically indexed)
    float4 aE0, aE1, aE2, aE3, aO0, aO1, aO2, aO3;
    f16x8 p0, p1, p2, p3, p4, p5, p6, p7;   // B set P
    f16x8 q0, q1, q2, q3, q4, q5, q6, q7;   // B set Q

#define A_LOAD4(R0_, R1_, R2_, R3_, STEP_) do {                             \
        const int st_ = (STEP_) < NSTEP ? (STEP_) : (NSTEP - 1);            \
        const float* p_ = xg + (size_t)st_ * 64;                            \
        R0_ = *(const float4*)(p_ + 0);                                     \
        R1_ = *(const float4*)(p_ + 16);                                    \
        R2_ = *(const float4*)(p_ + 32);                                    \
        R3_ = *(const float4*)(p_ + 48);                                    \
    } while (0)

#define B_LOAD8(R0_,R1_,R2_,R3_,R4_,R5_,R6_,R7_, STEP_) do {                \
        const int st_ = (STEP_) < NSTEP ? (STEP_) : (NSTEP - 1);            \
        const size_t oa_ = ((size_t)(st_ * 2))     << 9;                    \
        const size_t ob_ = ((size_t)(st_ * 2 + 1)) << 9;                    \
        R0_ = *(const f16x8*)(wpH0 + oa_);                                  \
        R1_ = *(const f16x8*)(wpH1 + oa_);                                  \
        R2_ = *(const f16x8*)(wpL0 + oa_);                                  \
        R3_ = *(const f16x8*)(wpL1 + oa_);                                  \
        R4_ = *(const f16x8*)(wpH0 + ob_);                                  \
        R5_ = *(const f16x8*)(wpH1 + ob_);                                  \
        R6_ = *(const f16x8*)(wpL0 + ob_);                                  \
        R7_ = *(const f16x8*)(wpL1 + ob_);                                  \
    } while (0)

    // store one float4 (half-granule) as hi/lo f16x4; g = gbase + 2*I_
#define ST_HG(BUF_, R_, I_) do {                                            \
        f16x4 h_, l_;                                                       \
        cvt_hilo4(R_, &h_, &l_);                                            \
        *(f16x4*)&A_lds[BUF_][0][gbase + 2 * (I_)][arow][ghalf] = h_;       \
        *(f16x4*)&A_lds[BUF_][1][gbase + 2 * (I_)][arow][ghalf] = l_;       \
    } while (0)

#define STORE_A4(BUF_, R0_, R1_, R2_, R3_) do {                             \
        ST_HG(BUF_, R0_, 0);                                                \
        ST_HG(BUF_, R1_, 1);                                                \
        ST_HG(BUF_, R2_, 2);                                                \
        ST_HG(BUF_, R3_, 3);                                                \
    } while (0)

#define MFMA16(A_, B_, C_) __builtin_amdgcn_mfma_f32_16x16x32_f16(A_, B_, C_, 0, 0, 0)

#define COMPUTE_CH(BUF_, K8O_, H0_, H1_, L0_, L1_) do {                     \
        f16x8 ah_[4], al_[4];                                               \
        _Pragma("unroll")                                                   \
        for (int mi_ = 0; mi_ < 4; ++mi_) {                                 \
            const int r_ = wr * 64 + mi_ * 16 + fr;                         \
            ah_[mi_] = *(const f16x8*)&A_lds[BUF_][0][(K8O_) + fq][r_][0];  \
            al_[mi_] = *(const f16x8*)&A_lds[BUF_][1][(K8O_) + fq][r_][0];  \
        }                                                                   \
        _Pragma("unroll")                                                   \
        for (int mi_ = 0; mi_ < 4; ++mi_) {                                 \
            accA[mi_][0] = MFMA16(ah_[mi_], H0_, accA[mi_][0]);             \
            accA[mi_][1] = MFMA16(ah_[mi_], H1_, accA[mi_][1]);             \
            accB[mi_][0] = MFMA16(ah_[mi_], L0_, accB[mi_][0]);             \
            accB[mi_][0] = MFMA16(al_[mi_], H0_, accB[mi_][0]);             \
            accB[mi_][1] = MFMA16(ah_[mi_], L1_, accB[mi_][1]);             \
            accB[mi_][1] = MFMA16(al_[mi_], H1_, accB[mi_][1]);             \
        }                                                                   \
    } while (0)

    // prologue: aE=A(0) -> buf0, aO=A(1), P=B(step 0)
    A_LOAD4(aE0, aE1, aE2, aE3, 0);
    A_LOAD4(aO0, aO1, aO2, aO3, 1);
    B_LOAD8(p0, p1, p2, p3, p4, p5, p6, p7, 0);
    STORE_A4(0, aE0, aE1, aE2, aE3);
    __syncthreads();

    for (int s = 0; s < NSTEP; s += 2) {
        // ---- even step s: buf0, B set P ----
        A_LOAD4(aE0, aE1, aE2, aE3, s + 2);
        B_LOAD8(q0, q1, q2, q3, q4, q5, q6, q7, s + 1);
        COMPUTE_CH(0, 0, p0, p1, p2, p3);
        COMPUTE_CH(0, 4, p4, p5, p6, p7);
        STORE_A4(1, aO0, aO1, aO2, aO3);   // A(s+1), loaded 1.5+ steps ago
        __syncthreads();

        // ---- odd step s+1: buf1, B set Q ----
        A_LOAD4(aO0, aO1, aO2, aO3, s + 3);
        B_LOAD8(p0, p1, p2, p3, p4, p5, p6, p7, s + 2);
        COMPUTE_CH(1, 0, q0, q1, q2, q3);
        COMPUTE_CH(1, 4, q4, q5, q6, q7);
        STORE_A4(0, aE0, aE1, aE2, aE3);   // A(s+2)
        __syncthreads();
    }

    // epilogue: combine, sigmoid, store (C layout: row=(lane>>4)*4+r, col=lane&15)
#pragma unroll
    for (int mi = 0; mi < 4; ++mi)
#pragma unroll
        for (int ni = 0; ni < 2; ++ni) {
            const int e = n0 + wc * 32 + ni * 16 + fr;
#pragma unroll
            for (int r = 0; r < 4; ++r) {
                const int m = m0 + wr * 64 + mi * 16 + fq * 4 + r;
                float logit = accA[mi][ni][r] + accB[mi][ni][r] * (1.f / 2048.f);
                S[(size_t)m * NEXP + e] = 1.f / (1.f + expf(-logit));
            }
        }
#undef A_LOAD4
#undef B_LOAD8
#undef ST_HG
#undef STORE_A4
#undef MFMA16
#undef COMPUTE_CH
}

// ================= K2: f32 routing + margin flagging =================
__launch_bounds__(256)
__global__ void route_flag_k(const float* __restrict__ S,
                             const float* __restrict__ bias,
                             float* __restrict__ out,
                             int* __restrict__ list,
                             int* __restrict__ count) {
    __shared__ float sraw[4][256];
    const int wv   = threadIdx.x >> 6;
    const int lane = threadIdx.x & 63;
    const int token = blockIdx.x * 4 + wv;
    const float NINF = -__builtin_inff();
    const float PINF =  __builtin_inff();

    const float* row = S + (size_t)token * NEXP;
    float4 v = *(const float4*)(row + lane * 4);
    *(float4*)&sraw[wv][lane * 4] = v;

    const int e0 = lane * 4;
    float4 bi4 = *(const float4*)(bias + e0);
    float b0 = v.x + bi4.x;
    float b1 = v.y + bi4.y;
    float b2 = v.z + bi4.z;
    float b3 = v.w + bi4.w;

    bool flag = false;

    float m1 = b0, m2 = NINF;
    if (b1 > m1) { m2 = m1; m1 = b1; } else if (b1 > m2) m2 = b1;
    if (b2 > m1) { m2 = m1; m1 = b2; } else if (b2 > m2) m2 = b2;
    if (b3 > m1) { m2 = m1; m1 = b3; } else if (b3 > m2) m2 = b3;
#pragma unroll
    for (int w = 1; w <= 4; w <<= 1) {
        float o1 = __shfl_xor(m1, w);
        float o2 = __shfl_xor(m2, w);
        float nm1 = fmaxf(m1, o1);
        float nm2 = fmaxf(fminf(m1, o1), fmaxf(m2, o2));
        m1 = nm1; m2 = nm2;
    }
    const float gs = m1 + m2;
    const int g = lane >> 3;

    int rank = 0;
#pragma unroll
    for (int j = 0; j < 8; ++j) {
        float gj = __shfl(gs, j * 8);
        rank += (gj > gs) || (gj == gs && j < g);
    }
    const bool sel = rank < 4;

    {
        float a = sel ? gs : PINF;
        float b = sel ? NINF : gs;
#pragma unroll
        for (int w = 1; w < 64; w <<= 1) {
            a = fminf(a, __shfl_xor(a, w));
            b = fmaxf(b, __shfl_xor(b, w));
        }
        flag |= (a - b) < 2.f * TAU;
    }

    if (!sel) { b0 = NINF; b1 = NINF; b2 = NINF; b3 = NINF; }

    int myidx = 0;
    float prev = 0.f;
#pragma unroll
    for (int it = 0; it < 9; ++it) {
        float bv = b0; int bi = e0;
        if (b1 > bv) { bv = b1; bi = e0 + 1; }
        if (b2 > bv) { bv = b2; bi = e0 + 2; }
        if (b3 > bv) { bv = b3; bi = e0 + 3; }
#pragma unroll
        for (int w = 1; w < 64; w <<= 1) {
            float ov = __shfl_xor(bv, w);
            int   oi = __shfl_xor(bi, w);
            if (ov > bv || (ov == bv && oi < bi)) { bv = ov; bi = oi; }
        }
        if (it > 0) flag |= (prev - bv) < TAU;
        prev = bv;
        if (it < 8) {
            if (lane == it) myidx = bi;
            if ((bi >> 2) == lane) {
                switch (bi & 3) {
                    case 0: b0 = NINF; break;
                    case 1: b1 = NINF; break;
                    case 2: b2 = NINF; break;
                    case 3: b3 = NINF; break;
                }
            }
        }
    }

    const bool anyflag = __any((int)flag);

    __syncthreads();

    float wval = (lane < 8) ? sraw[wv][myidx] : 0.f;
    float s = wval;
    s += __shfl_xor(s, 1);
    s += __shfl_xor(s, 2);
    s += __shfl_xor(s, 4);
    if (lane < 8) {
        float wout = wval / (s + 1e-20f) * 2.5f;
        out[(size_t)token * 8 + lane] = wout;
        out[(size_t)MTOK * 8 + (size_t)token * 8 + lane] = (float)myidx;
    }

    if (anyflag && lane == 0) {
        int f = atomicAdd(count, 1);
        if (f < CAPR) list[f] = token;
    }
}

// ================= K3: K-split f64 partial GEMM over flagged rows =================
__launch_bounds__(256)
__global__ void rescore_k(const float* __restrict__ X,
                          const float* __restrict__ W,
                          const int* __restrict__ list,
                          const int* __restrict__ count,
                          double* __restrict__ Ldp) {
    const int cnt = min(*count, CAPR);
    const int m0 = blockIdx.x * 64;
    if (m0 >= cnt) return;
    const int n0 = blockIdx.y * 64;
    const int ks = blockIdx.z;
    const int kbase = ks * KCH;

    __shared__ float As[16][66];
    __shared__ float Bs[16][66];
    const int tid = threadIdx.x;
    const int row = tid >> 2;
    const int c   = tid & 3;
    const int tm  = tid >> 4;
    const int tn  = tid & 15;

    const int gi = list[min(m0 + row, cnt - 1)];
    const float* xg = X + (size_t)gi * KDIM + c * 4;
    const float* wg = W + (size_t)(n0 + row) * KDIM + c * 4;

    double acc[4][4];
#pragma unroll
    for (int i = 0; i < 4; ++i)
#pragma unroll
        for (int j = 0; j < 4; ++j) acc[i][j] = 0.0;

    for (int k0 = kbase; k0 < kbase + KCH; k0 += 16) {
        float4 a = *(const float4*)(xg + k0);
        float4 b = *(const float4*)(wg + k0);
        __syncthreads();
        As[c * 4 + 0][row] = a.x; As[c * 4 + 1][row] = a.y;
        As[c * 4 + 2][row] = a.z; As[c * 4 + 3][row] = a.w;
        Bs[c * 4 + 0][row] = b.x; Bs[c * 4 + 1][row] = b.y;
        Bs[c * 4 + 2][row] = b.z; Bs[c * 4 + 3][row] = b.w;
        __syncthreads();
#pragma unroll
        for (int k = 0; k < 16; ++k) {
            double ad[4], bd[4];
#pragma unroll
            for (int i = 0; i < 4; ++i) ad[i] = (double)As[k][tm * 4 + i];
#pragma unroll
            for (int j = 0; j < 4; ++j) bd[j] = (double)Bs[k][tn * 4 + j];
#pragma unroll
            for (int i = 0; i < 4; ++i)
#pragma unroll
                for (int j = 0; j < 4; ++j)
                    acc[i][j] = fma(ad[i], bd[j], acc[i][j]);
        }
    }

#pragma unroll
    for (int i = 0; i < 4; ++i) {
        const int r = m0 + tm * 4 + i;
        if (r < cnt) {
#pragma unroll
            for (int j = 0; j < 4; ++j)
                Ldp[((size_t)ks * CAPR + r) * NEXP + n0 + tn * 4 + j] = acc[i][j];
        }
    }
}

// ================= K4: exact f64 routing for flagged tokens =================
__launch_bounds__(64)
__global__ void route_exact_k(const double* __restrict__ Ldp,
                              const float* __restrict__ bias,
                              const int* __restrict__ list,
                              const int* __restrict__ count,
                              float* __restrict__ out) {
    const int cnt = min(*count, CAPR);
    const int f = blockIdx.x;
    if (f >= cnt) return;
    const int lane = threadIdx.x;
    const int token = list[f];
    const double NINF = -__builtin_inf();

    const int e0 = lane * 4;
    double l0 = 0.0, l1 = 0.0, l2 = 0.0, l3 = 0.0;
#pragma unroll
    for (int s = 0; s < KSPLIT; ++s) {
        double4 p = *(const double4*)(Ldp + ((size_t)s * CAPR + f) * NEXP + e0);
        l0 += p.x; l1 += p.y; l2 += p.z; l3 += p.w;
    }

    double s0 = 1.0 / (1.0 + exp(-l0));
    double s1 = 1.0 / (1.0 + exp(-l1));
    double s2 = 1.0 / (1.0 + exp(-l2));
    double s3 = 1.0 / (1.0 + exp(-l3));

    float4 bi4 = *(const float4*)(bias + e0);
    double b0 = s0 + (double)bi4.x;
    double b1 = s1 + (double)bi4.y;
    double b2 = s2 + (double)bi4.z;
    double b3 = s3 + (double)bi4.w;

    double m1 = b0, m2 = NINF;
    if (b1 > m1) { m2 = m1; m1 = b1; } else if (b1 > m2) m2 = b1;
    if (b2 > m1) { m2 = m1; m1 = b2; } else if (b2 > m2) m2 = b2;
    if (b3 > m1) { m2 = m1; m1 = b3; } else if (b3 > m2) m2 = b3;
#pragma unroll
    for (int w = 1; w <= 4; w <<= 1) {
        double o1 = __shfl_xor(m1, w);
        double o2 = __shfl_xor(m2, w);
        double nm1 = fmax(m1, o1);
        double nm2 = fmax(fmin(m1, o1), fmax(m2, o2));
        m1 = nm1; m2 = nm2;
    }
    const double gs = m1 + m2;
    const int g = lane >> 3;

    int rank = 0;
#pragma unroll
    for (int j = 0; j < 8; ++j) {
        double gj = __shfl(gs, j * 8);
        rank += (gj > gs) || (gj == gs && j < g);
    }
    if (rank >= 4) { b0 = NINF; b1 = NINF; b2 = NINF; b3 = NINF; }

    int myidx = 0;
#pragma unroll
    for (int it = 0; it < 8; ++it) {
        double bv = b0; int bi = e0;
        if (b1 > bv) { bv = b1; bi = e0 + 1; }
        if (b2 > bv) { bv = b2; bi = e0 + 2; }
        if (b3 > bv) { bv = b3; bi = e0 + 3; }
#pragma unroll
        for (int w = 1; w < 64; w <<= 1) {
            double ov = __shfl_xor(bv, w);
            int    oi = __shfl_xor(bi, w);
            if (ov > bv || (ov == bv && oi < bi)) { bv = ov; bi = oi; }
        }
        if (lane == it) myidx = bi;
        if ((bi >> 2) == lane) {
            switch (bi & 3) {
                case 0: b0 = NINF; break;
                case 1: b1 = NINF; break;
                case 2: b2 = NINF; break;
                case 3: b3 = NINF; break;
            }
        }
    }

    double g0 = __shfl(s0, myidx >> 2);
    double g1 = __shfl(s1, myidx >> 2);
    double g2 = __shfl(s2, myidx >> 2);
    double g3 = __shfl(s3, myidx >> 2);
    const int ss = myidx & 3;
    double wval = (lane < 8) ? (ss == 0 ? g0 : ss == 1 ? g1 : ss == 2 ? g2 : g3) : 0.0;
    double s = wval;
    s += __shfl_xor(s, 1);
    s += __shfl_xor(s, 2);
    s += __shfl_xor(s, 4);
    if (lane < 8) {
        float wout = (float)(wval / (s + 1e-20) * 2.5);
        out[(size_t)token * 8 + lane] = wout;
        out[(size_t)MTOK * 8 + (size_t)token * 8 + lane] = (float)myidx;
    }
}

extern "C" void kernel_launch(void* const* d_in, const int* in_sizes, int n_in,
                              void* d_out, int out_size, void* d_ws, size_t ws_size,
                              hipStream_t stream) {
    const float* X    = (const float*)d_in[0];
    const float* W    = (const float*)d_in[1];
    const float* bias = (const float*)d_in[2];
    float* out = (float*)d_out;

    // ws: [0,16.8MB) Lf f32 scores, later aliased by Ldp f64 partials (rescore
    //     runs after route_flag, when Lf is dead). Then list, cnt, Wfrag.
    float*  Lf    = (float*)d_ws;
    double* Ldp   = (double*)d_ws;                        // 8*1024*256*8 = 16,777,216 B
    int*    list  = (int*)((char*)d_ws + 16777216);
    int*    cnt   = (int*)((char*)d_ws + 16777216 + CAPR * 4);
    f16*    Wfrag = (f16*)((char*)d_ws + 16777216 + 65536); // 7,340,032 B

    wconv_k<<<NEXP, 256, 0, stream>>>(W, Wfrag, cnt);

    gemm_v10_k<<<256, 512, 0, stream>>>(X, Wfrag, Lf);

    route_flag_k<<<MTOK / 4, 256, 0, stream>>>(Lf, bias, out, list, cnt);

    dim3 g3(CAPR / 64, NEXP / 64, KSPLIT);
    rescore_k<<<g3, 256, 0, stream>>>(X, W, list, cnt, Ldp);

    route_exact_k<<<CAPR, 64, 0, stream>>>(Ldp, bias, list, cnt, out);
}